// Round 5
// 215.177 us; speedup vs baseline: 1.0794x; 1.0794x over previous
//
#include <hip/hip_runtime.h>
#include <math.h>

#define BB 8
#define NN 2048
#define LL 2048
#define QQ 512
#define DD 512

typedef float f4 __attribute__((ext_vector_type(4)));

__device__ __forceinline__ void top3_insert(float v, int i, float& m0,
                                            float& m1, float& m2, int& j0,
                                            int& j1, int& j2) {
  bool gt0 = v > m0, gt1 = v > m1, gt2 = v > m2;
  float nv2 = gt1 ? m1 : (gt2 ? v : m2);
  int   ni2 = gt1 ? j1 : (gt2 ? i : j2);
  float nv1 = gt0 ? m0 : (gt1 ? v : m1);
  int   ni1 = gt0 ? j0 : (gt1 ? i : j1);
  m0 = gt0 ? v : m0;
  j0 = gt0 ? i : j0;
  m1 = nv1; j1 = ni1; m2 = nv2; j2 = ni2;
}

// -------- Kernel A: per-wave partial top-3 over a 64-wide n-chunk ---------
// Round-0 verified structure; chunk width 32 -> 64 (part halved to 8 MiB),
// logits loads non-temporal (stream-once; don't evict part/embs from L2/L3).
// Grid (8 lt, 4 h, 16 = b*2+ns), block 256 = 4 waves; wave g owns chunk
// ns*4+g (64 n's). Lane u tracks 4 l's via float4 loads along L; 8-deep
// explicit load batching. Each thread writes 4 partial float4s (coalesced).
__global__ __launch_bounds__(256) void topk_part_kernel(
    const float* __restrict__ logits, float4* __restrict__ part) {
  const int u     = threadIdx.x & 63;
  const int g     = threadIdx.x >> 6;
  const int lt    = blockIdx.x;       // 0..7
  const int h     = blockIdx.y;       // 0..3
  const int b     = blockIdx.z >> 1;  // 0..7
  const int ns    = blockIdx.z & 1;   // 0..1
  const int chunk = ns * 4 + g;       // 0..7
  const int n0    = chunk * 64;
  const int l4    = lt * 256 + u * 4;

  const float* base = logits + ((size_t)(b * NN + h * QQ + n0) * LL) + l4;

  float v0[4], v1[4], v2[4];
  int   i0[4], i1[4], i2[4];
#pragma unroll
  for (int j = 0; j < 4; ++j) {
    v0[j] = v1[j] = v2[j] = -INFINITY;
    i0[j] = i1[j] = i2[j] = 0;
  }

  f4 buf[8];
  for (int t = 0; t < 8; ++t) {  // 8 batches of 8 n's, 8 loads in flight
#pragma unroll
    for (int p = 0; p < 8; ++p)
      buf[p] = __builtin_nontemporal_load(
          (const f4*)(base + (size_t)(t * 8 + p) * LL));
#pragma unroll
    for (int p = 0; p < 8; ++p) {
      const int i = n0 + t * 8 + p;
      top3_insert(buf[p][0], i, v0[0], v1[0], v2[0], i0[0], i1[0], i2[0]);
      top3_insert(buf[p][1], i, v0[1], v1[1], v2[1], i0[1], i1[1], i2[1]);
      top3_insert(buf[p][2], i, v0[2], v1[2], v2[2], i0[2], i1[2], i2[2]);
      top3_insert(buf[p][3], i, v0[3], v1[3], v2[3], i0[3], i1[3], i2[3]);
    }
  }

  // part[((b*4+h)*8 + chunk)*LL + l]
  float4* pout = part + ((size_t)((b * 4 + h) * 8 + chunk)) * LL + l4;
#pragma unroll
  for (int j = 0; j < 4; ++j) {
    unsigned int pi = (unsigned int)i0[j] | ((unsigned int)i1[j] << 9) |
                      ((unsigned int)i2[j] << 18);
    pout[j] = make_float4(v0[j], v1[j], v2[j], __uint_as_float(pi));
  }
}

// -------- Kernel B: fused merge + softmax + gather + transpose store ------
// Round-0 verified structure; merge reads 8 partials (was 16), out stores
// non-temporal. Grid (128 l-tiles, 8 b), block 256 = 4 waves; 16 l x 512 d
// per block. Phase 0: threads 0..63 merge the 8 chunk-partials of one (h,l),
// softmax, stash weights+indices in LDS. Phase 1: wave w handles l's
// w*4..w*4+3; all 64 lanes read the SAME emb row contiguously (float4/lane)
// -> weighted sum -> LDS tile. Phase 2: transposed float4-over-l stores.
__global__ __launch_bounds__(256) void combine_kernel(
    const float4* __restrict__ part,
    const float* __restrict__ emb0, const float* __restrict__ emb1,
    const float* __restrict__ emb2, const float* __restrict__ emb3,
    float* __restrict__ out) {
  const int u    = threadIdx.x & 63;
  const int w    = threadIdx.x >> 6;
  const int lblk = blockIdx.x * 16;
  const int b    = blockIdx.y;

  __shared__ float wt_s[4][16][3];
  __shared__ int   rid_s[4][16][3];
  __shared__ float tile[16][516];  // stride 516: 2-way bank alias only (free)

  if (threadIdx.x < 64) {
    const int h  = threadIdx.x >> 4;
    const int il = threadIdx.x & 15;
    const int l  = lblk + il;
    const float4* pp = part + ((size_t)(b * 4 + h) * 8) * LL + l;

    float m0 = -INFINITY, m1 = -INFINITY, m2 = -INFINITY;
    int   j0 = 0, j1 = 0, j2 = 0;
#pragma unroll
    for (int c = 0; c < 8; ++c) {
      float4 P = pp[(size_t)c * LL];
      unsigned int pi = __float_as_uint(P.w);
      top3_insert(P.x, pi & 511, m0, m1, m2, j0, j1, j2);
      top3_insert(P.y, (pi >> 9) & 511, m0, m1, m2, j0, j1, j2);
      top3_insert(P.z, (pi >> 18) & 511, m0, m1, m2, j0, j1, j2);
    }
    float e1 = __expf(m1 - m0), e2 = __expf(m2 - m0);
    float inv = 1.0f / (1.0f + e1 + e2);
    wt_s[h][il][0] = inv;
    wt_s[h][il][1] = e1 * inv;
    wt_s[h][il][2] = e2 * inv;
    rid_s[h][il][0] = j0;
    rid_s[h][il][1] = j1;
    rid_s[h][il][2] = j2;
  }
  __syncthreads();

  const float* embs[4] = {emb0, emb1, emb2, emb3};

#pragma unroll
  for (int il = 0; il < 4; ++il) {
    const int ll = w * 4 + il;
    float wt[12];
    const float* rows[12];
#pragma unroll
    for (int h = 0; h < 4; ++h) {
#pragma unroll
      for (int k = 0; k < 3; ++k) {
        wt[h * 3 + k]   = wt_s[h][ll][k];                       // broadcast
        rows[h * 3 + k] = embs[h] + (size_t)rid_s[h][ll][k] * DD;
      }
    }
#pragma unroll
    for (int p = 0; p < 2; ++p) {
      const int d = p * 256 + u * 4;
      float a0 = 0.f, a1 = 0.f, a2 = 0.f, a3 = 0.f;
#pragma unroll
      for (int m = 0; m < 12; ++m) {
        const float4 e = *(const float4*)(rows[m] + d);  // coalesced 1KB/inst
        a0 += wt[m] * e.x;
        a1 += wt[m] * e.y;
        a2 += wt[m] * e.z;
        a3 += wt[m] * e.w;
      }
      *(float4*)&tile[ll][d] = make_float4(a0, a1, a2, a3);
    }
  }
  __syncthreads();

  const int l0  = (threadIdx.x & 3) * 4;
  const int dof = threadIdx.x >> 2;  // 0..63
  float* outb = out + (size_t)b * DD * LL + lblk + l0;
#pragma unroll
  for (int dd = 0; dd < 512; dd += 64) {
    const int d = dd + dof;
    f4 r;
    r[0] = tile[l0 + 0][d];
    r[1] = tile[l0 + 1][d];
    r[2] = tile[l0 + 2][d];
    r[3] = tile[l0 + 3][d];
    __builtin_nontemporal_store(r, (f4*)(outb + (size_t)d * LL));
  }
}

extern "C" void kernel_launch(void* const* d_in, const int* in_sizes, int n_in,
                              void* d_out, int out_size, void* d_ws,
                              size_t ws_size, hipStream_t stream) {
  const float* logits = (const float*)d_in[0];
  const float* emb0   = (const float*)d_in[1];
  const float* emb1   = (const float*)d_in[2];
  const float* emb2   = (const float*)d_in[3];
  const float* emb3   = (const float*)d_in[4];
  float*       out    = (float*)d_out;
  float4*      part   = (float4*)d_ws;  // 8*4*8*2048 float4 = 8 MiB

  dim3 ga(8, 4, 16);  // 512 blocks, 8 waves/CU, no LDS
  topk_part_kernel<<<ga, 256, 0, stream>>>(logits, part);

  dim3 gb(LL / 16, BB);  // 1024 blocks
  combine_kernel<<<gb, 256, 0, stream>>>(part, emb0, emb1, emb2, emb3, out);
}

// Round 7
// 214.127 us; speedup vs baseline: 1.0847x; 1.0049x over previous
//
#include <hip/hip_runtime.h>
#include <math.h>

#define BB 8
#define NN 2048
#define LL 2048
#define QQ 512
#define DD 512

typedef float f4 __attribute__((ext_vector_type(4)));

__device__ __forceinline__ void top3_insert(float v, int i, float& m0,
                                            float& m1, float& m2, int& j0,
                                            int& j1, int& j2) {
  bool gt0 = v > m0, gt1 = v > m1, gt2 = v > m2;
  float nv2 = gt1 ? m1 : (gt2 ? v : m2);
  int   ni2 = gt1 ? j1 : (gt2 ? i : j2);
  float nv1 = gt0 ? m0 : (gt1 ? v : m1);
  int   ni1 = gt0 ? j0 : (gt1 ? i : j1);
  m0 = gt0 ? v : m0;
  j0 = gt0 ? i : j0;
  m1 = nv1; j1 = ni1; m2 = nv2; j2 = ni2;
}

__device__ __forceinline__ unsigned bf16_rne(float f) {
  unsigned u = __float_as_uint(f);
  return (u + 0x7FFFu + ((u >> 16) & 1u)) >> 16;
}

// -------- Kernel P: convert 4x(512x512) f32 emb tables to bf16 in ws ------
// 4 MB read, 2 MB write (~2 us). The bf16 table (2 MiB) fits an XCD L2 with
// room to spare, turning kernel B's gather into L2 hits.
__global__ __launch_bounds__(256) void cvt_kernel(
    const float* __restrict__ e0, const float* __restrict__ e1,
    const float* __restrict__ e2, const float* __restrict__ e3,
    unsigned short* __restrict__ ebf) {
  const float* embs[4] = {e0, e1, e2, e3};
  const int h = blockIdx.y;
  const int i = (blockIdx.x * 256 + threadIdx.x) * 8;  // 8 f32 per thread
  const float* src = embs[h] + i;
  const float4 x = *(const float4*)src;
  const float4 y = *(const float4*)(src + 4);
  uint4 o;
  o.x = bf16_rne(x.x) | (bf16_rne(x.y) << 16);
  o.y = bf16_rne(x.z) | (bf16_rne(x.w) << 16);
  o.z = bf16_rne(y.x) | (bf16_rne(y.y) << 16);
  o.w = bf16_rne(y.z) | (bf16_rne(y.w) << 16);
  *(uint4*)(ebf + (size_t)h * QQ * DD + i) = o;
}

// -------- Kernel A: per-wave partial top-3 over a 64-wide n-chunk ---------
// (round-5 passing structure; part buffer typed f4 throughout)
// Grid (8 lt, 4 h, 16 = b*2+ns), block 256 = 4 waves; wave g owns chunk
// ns*4+g (64 n's). Lane u tracks 4 l's via nt float4 loads along L; 8-deep
// explicit load batching. Each thread writes 4 partial f4s (coalesced).
__global__ __launch_bounds__(256) void topk_part_kernel(
    const float* __restrict__ logits, f4* __restrict__ part) {
  const int u     = threadIdx.x & 63;
  const int g     = threadIdx.x >> 6;
  const int lt    = blockIdx.x;       // 0..7
  const int h     = blockIdx.y;       // 0..3
  const int b     = blockIdx.z >> 1;  // 0..7
  const int ns    = blockIdx.z & 1;   // 0..1
  const int chunk = ns * 4 + g;       // 0..7
  const int n0    = chunk * 64;
  const int l4    = lt * 256 + u * 4;

  const float* base = logits + ((size_t)(b * NN + h * QQ + n0) * LL) + l4;

  float v0[4], v1[4], v2[4];
  int   i0[4], i1[4], i2[4];
#pragma unroll
  for (int j = 0; j < 4; ++j) {
    v0[j] = v1[j] = v2[j] = -INFINITY;
    i0[j] = i1[j] = i2[j] = 0;
  }

  f4 buf[8];
  for (int t = 0; t < 8; ++t) {  // 8 batches of 8 n's, 8 loads in flight
#pragma unroll
    for (int p = 0; p < 8; ++p)
      buf[p] = __builtin_nontemporal_load(
          (const f4*)(base + (size_t)(t * 8 + p) * LL));
#pragma unroll
    for (int p = 0; p < 8; ++p) {
      const int i = n0 + t * 8 + p;
      top3_insert(buf[p][0], i, v0[0], v1[0], v2[0], i0[0], i1[0], i2[0]);
      top3_insert(buf[p][1], i, v0[1], v1[1], v2[1], i0[1], i1[1], i2[1]);
      top3_insert(buf[p][2], i, v0[2], v1[2], v2[2], i0[2], i1[2], i2[2]);
      top3_insert(buf[p][3], i, v0[3], v1[3], v2[3], i0[3], i1[3], i2[3]);
    }
  }

  // part[((b*4+h)*8 + chunk)*LL + l]
  f4* pout = part + ((size_t)((b * 4 + h) * 8 + chunk)) * LL + l4;
#pragma unroll
  for (int j = 0; j < 4; ++j) {
    unsigned int pi = (unsigned int)i0[j] | ((unsigned int)i1[j] << 9) |
                      ((unsigned int)i2[j] << 18);
    f4 rec = {v0[j], v1[j], v2[j], __uint_as_float(pi)};
    pout[j] = rec;
  }
}

// -------- Kernel B: fused merge + softmax + bf16 gather + transpose -------
// Round-5 verified structure; gather now reads the bf16 table (uint2/lane,
// shift-reconstruct to f32, f32 accumulate). part reads are non-temporal
// (read-once) so they don't evict the bf16 table from L2.
__global__ __launch_bounds__(256) void combine_kernel(
    const f4* __restrict__ part, const unsigned short* __restrict__ ebf,
    float* __restrict__ out) {
  const int u    = threadIdx.x & 63;
  const int w    = threadIdx.x >> 6;
  const int lblk = blockIdx.x * 16;
  const int b    = blockIdx.y;

  __shared__ float wt_s[4][16][3];
  __shared__ int   rid_s[4][16][3];
  __shared__ float tile[16][516];  // stride 516: 2-way bank alias only (free)

  if (threadIdx.x < 64) {
    const int h  = threadIdx.x >> 4;
    const int il = threadIdx.x & 15;
    const int l  = lblk + il;
    const f4* pp = part + ((size_t)(b * 4 + h) * 8) * LL + l;

    float m0 = -INFINITY, m1 = -INFINITY, m2 = -INFINITY;
    int   j0 = 0, j1 = 0, j2 = 0;
#pragma unroll
    for (int c = 0; c < 8; ++c) {
      const f4 P = __builtin_nontemporal_load(pp + (size_t)c * LL);
      unsigned int pi = __float_as_uint(P[3]);
      top3_insert(P[0], pi & 511, m0, m1, m2, j0, j1, j2);
      top3_insert(P[1], (pi >> 9) & 511, m0, m1, m2, j0, j1, j2);
      top3_insert(P[2], (pi >> 18) & 511, m0, m1, m2, j0, j1, j2);
    }
    float e1 = __expf(m1 - m0), e2 = __expf(m2 - m0);
    float inv = 1.0f / (1.0f + e1 + e2);
    wt_s[h][il][0] = inv;
    wt_s[h][il][1] = e1 * inv;
    wt_s[h][il][2] = e2 * inv;
    rid_s[h][il][0] = j0;
    rid_s[h][il][1] = j1;
    rid_s[h][il][2] = j2;
  }
  __syncthreads();

#pragma unroll
  for (int il = 0; il < 4; ++il) {
    const int ll = w * 4 + il;
    float wt[12];
    const unsigned short* rows[12];
#pragma unroll
    for (int h = 0; h < 4; ++h) {
#pragma unroll
      for (int k = 0; k < 3; ++k) {
        wt[h * 3 + k]   = wt_s[h][ll][k];  // wave-uniform LDS broadcast
        rows[h * 3 + k] = ebf + ((size_t)h * QQ + rid_s[h][ll][k]) * DD;
      }
    }
#pragma unroll
    for (int p = 0; p < 2; ++p) {
      const int d = p * 256 + u * 4;
      float a0 = 0.f, a1 = 0.f, a2 = 0.f, a3 = 0.f;
#pragma unroll
      for (int m = 0; m < 12; ++m) {
        const uint2 e = *(const uint2*)(rows[m] + d);  // 4 bf16, L2-hit
        a0 += wt[m] * __uint_as_float(e.x << 16);
        a1 += wt[m] * __uint_as_float(e.x & 0xFFFF0000u);
        a2 += wt[m] * __uint_as_float(e.y << 16);
        a3 += wt[m] * __uint_as_float(e.y & 0xFFFF0000u);
      }
      *(float4*)&tile[ll][d] = make_float4(a0, a1, a2, a3);
    }
  }
  __syncthreads();

  const int l0  = (threadIdx.x & 3) * 4;
  const int dof = threadIdx.x >> 2;  // 0..63
  float* outb = out + (size_t)b * DD * LL + lblk + l0;
#pragma unroll
  for (int dd = 0; dd < 512; dd += 64) {
    const int d = dd + dof;
    f4 r;
    r[0] = tile[l0 + 0][d];
    r[1] = tile[l0 + 1][d];
    r[2] = tile[l0 + 2][d];
    r[3] = tile[l0 + 3][d];
    __builtin_nontemporal_store(r, (f4*)(outb + (size_t)d * LL));
  }
}

extern "C" void kernel_launch(void* const* d_in, const int* in_sizes, int n_in,
                              void* d_out, int out_size, void* d_ws,
                              size_t ws_size, hipStream_t stream) {
  const float* logits = (const float*)d_in[0];
  const float* emb0   = (const float*)d_in[1];
  const float* emb1   = (const float*)d_in[2];
  const float* emb2   = (const float*)d_in[3];
  const float* emb3   = (const float*)d_in[4];
  float*       out    = (float*)d_out;
  f4*          part   = (f4*)d_ws;  // 8*4*8*2048 f4 = 8 MiB
  unsigned short* ebf = (unsigned short*)((char*)d_ws + (8u << 20));  // 2 MiB

  dim3 gc(128, 4);  // bf16 conversion of the 4 emb tables
  cvt_kernel<<<gc, 256, 0, stream>>>(emb0, emb1, emb2, emb3, ebf);

  dim3 ga(8, 4, 16);  // 512 blocks, no LDS
  topk_part_kernel<<<ga, 256, 0, stream>>>(logits, part);

  dim3 gb(LL / 16, BB);  // 1024 blocks
  combine_kernel<<<gb, 256, 0, stream>>>(part, ebf, out);
}